// Round 15
// baseline (417.124 us; speedup 1.0000x reference)
//
#include <hip/hip_runtime.h>
#include <hip/hip_bf16.h>

#define V_ 32000
#define D_ 256
#define H_ 512
#define B_ 32
#define T_ 64
#define NSL 8   // column slices per batch; GRU grid = 32*NSL = 256

typedef __attribute__((ext_vector_type(8))) __bf16 bf16x8;
typedef __attribute__((ext_vector_type(4))) float f32x4;
typedef _Float16 f16x2 __attribute__((ext_vector_type(2)));
typedef unsigned int u32t;
typedef unsigned short u16t;
typedef unsigned long long u64t;

__device__ __forceinline__ u32t pack_h16(float a, float b) {
  union { _Float16 h; unsigned short u; } lo, hi;
  lo.h = (_Float16)a; hi.h = (_Float16)b;
  return (u32t)lo.u | ((u32t)hi.u << 16);
}

__device__ __forceinline__ float f16u_to_f(u16t u) {
  union { _Float16 h; unsigned short u; } x;
  x.u = u;
  return (float)x.h;
}

__device__ __forceinline__ float dot2(u32t w, u32t h, float acc) {
#if __has_builtin(__builtin_amdgcn_fdot2)
  return __builtin_amdgcn_fdot2(__builtin_bit_cast(f16x2, w),
                                __builtin_bit_cast(f16x2, h), acc, false);
#else
  f16x2 a = __builtin_bit_cast(f16x2, w);
  f16x2 b = __builtin_bit_cast(f16x2, h);
  return acc + (float)a.x * (float)b.x + (float)a.y * (float)b.y;
#endif
}

__device__ __forceinline__ void gld_lds16(const void* g, void* l) {
  __builtin_amdgcn_global_load_lds((const __attribute__((address_space(1))) void*)g,
                                   (__attribute__((address_space(3))) void*)l,
                                   16, 0, 0);
}

__device__ __forceinline__ u32t ld_rlx(const u32t* p) {
  return __hip_atomic_load(p, __ATOMIC_RELAXED, __HIP_MEMORY_SCOPE_AGENT);
}
__device__ __forceinline__ void st_rlx(u32t* p, u32t v) {
  __hip_atomic_store(p, v, __ATOMIC_RELAXED, __HIP_MEMORY_SCOPE_AGENT);
}

// ---------------- merged setup: transpose + weight packs/init + x-projections -------
// blocks [0,4000):      Wout -> WoutT transpose (500 x 8 tile grid)
// blocks [4000,4448):   Wg/Wc f16 packs + tagged HBT/RHT init
// blocks [4448,5984):   pre_g / pre_c x-projections (256 x 6)
__global__ __launch_bounds__(256) void k_setup(const float* __restrict__ Wout,
                                               __hip_bfloat16* __restrict__ WoutT,
                                               const float* __restrict__ Wg,
                                               const float* __restrict__ Wc,
                                               const float* __restrict__ enc,
                                               uint4* __restrict__ Wg2,
                                               uint4* __restrict__ Wc2,
                                               u32t* __restrict__ HBT,
                                               u32t* __restrict__ RHT,
                                               const int* __restrict__ widx,
                                               const float* __restrict__ embW,
                                               const float* __restrict__ bg,
                                               const float* __restrict__ bc,
                                               float* __restrict__ pre_g,
                                               float* __restrict__ pre_c) {
  int blk = blockIdx.x;
  int tid = threadIdx.x;

  if (blk < 4000) {
    __shared__ float tile[64][65];
    int v0 = (blk % 500) * 64;
    int h0 = (blk / 500) * 64;
#pragma unroll
    for (int i = 0; i < 16; ++i) {
      int idx = i * 256 + tid;
      int r = idx >> 6;
      int c = idx & 63;
      tile[r][c] = Wout[(size_t)(h0 + r) * V_ + v0 + c];
    }
    __syncthreads();
#pragma unroll
    for (int i = 0; i < 16; ++i) {
      int idx = i * 256 + tid;
      int rv = idx >> 6;
      int ch = idx & 63;
      WoutT[(size_t)(v0 + rv) * H_ + h0 + ch] = __float2bfloat16(tile[ch][rv]);
    }
  } else if (blk < 4448) {
    int pblk = blk - 4000;
    if (pblk < 256) {
      int gid = pblk * 256 + tid;
      int ks = gid & 3;
      int cq = (gid >> 2) & 127;
      int it = (gid >> 9) & 15;
      int s = gid >> 13;
      int j = (cq < 64) ? (s * 64 + cq) : (512 + s * 64 + (cq - 64));
      int k0 = ks * 128 + it * 8;
      uint4 v;
      v.x = pack_h16(Wg[(size_t)(256 + k0 + 0) * 1024 + j], Wg[(size_t)(256 + k0 + 1) * 1024 + j]);
      v.y = pack_h16(Wg[(size_t)(256 + k0 + 2) * 1024 + j], Wg[(size_t)(256 + k0 + 3) * 1024 + j]);
      v.z = pack_h16(Wg[(size_t)(256 + k0 + 4) * 1024 + j], Wg[(size_t)(256 + k0 + 5) * 1024 + j]);
      v.w = pack_h16(Wg[(size_t)(256 + k0 + 6) * 1024 + j], Wg[(size_t)(256 + k0 + 7) * 1024 + j]);
      Wg2[gid] = v;
    } else if (pblk < 384) {
      int gid = (pblk - 256) * 256 + tid;
      int ks8 = gid & 7;
      int cq2 = (gid >> 3) & 63;
      int it = (gid >> 9) & 7;
      int s = gid >> 12;
      int jc = s * 64 + cq2;
      int k0 = ks8 * 64 + it * 8;
      uint4 v;
      v.x = pack_h16(Wc[(size_t)(256 + k0 + 0) * 512 + jc], Wc[(size_t)(256 + k0 + 1) * 512 + jc]);
      v.y = pack_h16(Wc[(size_t)(256 + k0 + 2) * 512 + jc], Wc[(size_t)(256 + k0 + 3) * 512 + jc]);
      v.z = pack_h16(Wc[(size_t)(256 + k0 + 4) * 512 + jc], Wc[(size_t)(256 + k0 + 5) * 512 + jc]);
      v.w = pack_h16(Wc[(size_t)(256 + k0 + 6) * 512 + jc], Wc[(size_t)(256 + k0 + 7) * 512 + jc]);
      Wc2[gid] = v;
    } else {
      int gid = (pblk - 384) * 256 + tid;
      int b = gid >> 9, k = gid & 511;
      u32t hv = pack_h16(enc[b * H_ + k], 0.f) & 0xffffu;
      st_rlx(&HBT[gid], hv);
      st_rlx(&RHT[gid], 0xFFFF0000u);
    }
  } else {
    __shared__ __align__(16) float x2[D_][8];
    __shared__ int wid[8];
    int idx = blk - 4448;
    int bx = idx & 255;
    int by = idx >> 8;
    int n0 = bx * 8;
    if (tid < 8) wid[tid] = widx[n0 + tid];
    __syncthreads();
#pragma unroll
    for (int i = 0; i < 8; ++i)
      x2[tid][i] = embW[(size_t)wid[i] * D_ + tid];
    __syncthreads();

    float acc[8];
    if (by < 4) {
      int J = by * 256 + tid;
      float bias = bg[J];
#pragma unroll
      for (int i = 0; i < 8; ++i) acc[i] = bias;
      for (int d = 0; d < D_; ++d) {
        float4 xa = *(const float4*)&x2[d][0];
        float4 xb = *(const float4*)&x2[d][4];
        float w = Wg[(size_t)d * 1024 + J];
        acc[0] = fmaf(xa.x, w, acc[0]); acc[1] = fmaf(xa.y, w, acc[1]);
        acc[2] = fmaf(xa.z, w, acc[2]); acc[3] = fmaf(xa.w, w, acc[3]);
        acc[4] = fmaf(xb.x, w, acc[4]); acc[5] = fmaf(xb.y, w, acc[5]);
        acc[6] = fmaf(xb.z, w, acc[6]); acc[7] = fmaf(xb.w, w, acc[7]);
      }
#pragma unroll
      for (int i = 0; i < 8; ++i)
        pre_g[(size_t)(n0 + i) * 1024 + J] = acc[i];
    } else {
      int Jc = (by - 4) * 256 + tid;
      float bias = bc[Jc];
#pragma unroll
      for (int i = 0; i < 8; ++i) acc[i] = bias;
      for (int d = 0; d < D_; ++d) {
        float4 xa = *(const float4*)&x2[d][0];
        float4 xb = *(const float4*)&x2[d][4];
        float w = Wc[(size_t)d * 512 + Jc];
        acc[0] = fmaf(xa.x, w, acc[0]); acc[1] = fmaf(xa.y, w, acc[1]);
        acc[2] = fmaf(xa.z, w, acc[2]); acc[3] = fmaf(xa.w, w, acc[3]);
        acc[4] = fmaf(xb.x, w, acc[4]); acc[5] = fmaf(xb.y, w, acc[5]);
        acc[6] = fmaf(xb.z, w, acc[6]); acc[7] = fmaf(xb.w, w, acc[7]);
      }
#pragma unroll
      for (int i = 0; i < 8; ++i)
        pre_c[(size_t)(n0 + i) * 512 + Jc] = acc[i];
    }
  }
}

// ---------------- GRU v7: tag-embedded payload exchange (proven ~196 us) ------------
__global__ __launch_bounds__(512, 2) void k_gru7(const int* __restrict__ num_words,
                                                 const uint4* __restrict__ Wg2,
                                                 const uint4* __restrict__ Wc2,
                                                 const float* __restrict__ pre_g,
                                                 const float* __restrict__ pre_c,
                                                 u32t* __restrict__ RHT,
                                                 u32t* __restrict__ HBT,
                                                 u32t* __restrict__ A32) {
  __shared__ __align__(16) u32t h2_l[256];
  __shared__ __align__(16) u32t rh2_l[256];
  __shared__ float u_l[64];
  int bid = blockIdx.x;
  int b = bid & 31;
  int s = bid >> 5;
  int tid = threadIdx.x;
  int nw = num_words[b];

  int cq = tid >> 2, ks = tid & 3;
  int j1 = (cq < 64) ? (s * 64 + cq) : (512 + s * 64 + (cq - 64));
  int cq2 = tid >> 3, ks8 = tid & 7;
  int jc = s * 64 + cq2;

  uint4 wg[16];
#pragma unroll
  for (int i = 0; i < 16; ++i) {
    int ii = (i + ks) & 15;
    wg[i] = Wg2[(((size_t)s * 16 + ii) * 128 + cq) * 4 + ks];
  }
  uint4 wc[8];
#pragma unroll
  for (int i = 0; i < 8; ++i) {
    int ii = (i + ks8) & 7;
    wc[i] = Wc2[(((size_t)s * 8 + ii) * 64 + cq2) * 8 + ks8];
  }

  u32t* HBp = HBT + (size_t)b * 512;
  u32t* RHp = RHT + (size_t)b * 512;
  bool pub1 = (ks == 0) && (cq < 64);
  bool ulane = (ks == 0) && (cq >= 64);
  bool pub2 = (ks8 == 0);
  bool writer2 = pub2 && ((cq2 & 1) == 0);

  for (int t = 0; t < T_; ++t) {
    float pg = pre_g[((size_t)b * T_ + t) * 1024 + j1];
    float pc = pre_c[((size_t)b * T_ + t) * 512 + jc];

    __syncthreads();
    {
      u32t want = (u32t)t << 16;
      u32t v;
      do { v = ld_rlx(&HBp[tid]); } while ((v & 0xffff0000u) != want);
      ((volatile u16t*)h2_l)[tid] = (u16t)v;
    }
    __syncthreads();

    float a0 = 0.f, a1 = 0.f, a2s = 0.f, a3 = 0.f;
    const uint4* h4 = (const uint4*)h2_l;
#pragma unroll
    for (int i = 0; i < 16; ++i) {
      int ii = (i + ks) & 15;
      uint4 hv = h4[ks * 16 + ii];
      a0 = dot2(wg[i].x, hv.x, a0);
      a1 = dot2(wg[i].y, hv.y, a1);
      a2s = dot2(wg[i].z, hv.z, a2s);
      a3 = dot2(wg[i].w, hv.w, a3);
    }
    float a = (a0 + a1) + (a2s + a3);
    a += __shfl_xor(a, 1);
    a += __shfl_xor(a, 2);
    float gate = 1.f / (1.f + __expf(-(a + pg)));
    if (cq < 64) {
      float hh = f16u_to_f(((const u16t*)h2_l)[s * 64 + cq]);
      if (pub1)
        st_rlx(&RHp[s * 64 + cq],
               (pack_h16(gate * hh, 0.f) & 0xffffu) | ((u32t)(t + 1) << 16));
    } else if (ulane) {
      u_l[cq - 64] = gate;
    }

    {
      u32t want = (u32t)(t + 1) << 16;
      u32t v;
      do { v = ld_rlx(&RHp[tid]); } while ((v & 0xffff0000u) != want);
      ((volatile u16t*)rh2_l)[tid] = (u16t)v;
    }
    __syncthreads();

    float c0 = 0.f, c1 = 0.f, c2 = 0.f, c3 = 0.f;
    const uint4* r4 = (const uint4*)rh2_l;
#pragma unroll
    for (int i = 0; i < 8; ++i) {
      int ii = (i + ks8) & 7;
      uint4 rv = r4[ks8 * 8 + ii];
      c0 = dot2(wc[i].x, rv.x, c0);
      c1 = dot2(wc[i].y, rv.y, c1);
      c2 = dot2(wc[i].z, rv.z, c2);
      c3 = dot2(wc[i].w, rv.w, c3);
    }
    float a2 = (c0 + c1) + (c2 + c3);
    a2 += __shfl_xor(a2, 1);
    a2 += __shfl_xor(a2, 2);
    a2 += __shfl_xor(a2, 4);
    float cv = tanhf(a2 + pc);
    float uu = u_l[cq2];
    float hold = f16u_to_f(((const u16t*)h2_l)[jc]);
    float hn = uu * hold + (1.f - uu) * cv;
    bool live = t < nw;
    float hnext = live ? hn : hold;
    if (pub2)
      st_rlx(&HBp[s * 64 + cq2],
             (pack_h16(hnext, 0.f) & 0xffffu) | ((u32t)(t + 1) << 16));
    u32t ma = (u32t)__hip_bfloat16_raw(__float2bfloat16(live ? hn : 0.f)).x;
    u32t oa = (u32t)__shfl_xor((int)ma, 8);
    if (writer2)
      A32[(((size_t)b * T_ + t) * 512 + jc) >> 1] = ma | (oa << 16);
  }
}

// ---------------- projection v2: 256x256 tile, counted-vmcnt pipeline ----------------
// 512 thr / 8 waves (2m x 4n); per-wave output 128x64; LDS 2 dbuf x (A+B) = 128 KB.
// Per K-tile: 4 phases {12 ds_read -> stage-issue (phases 0-1, other buffer) ->
// setprio+16 MFMA -> raw s_barrier}; vmcnt(0) once per K-tile (2-3 phase latency
// cover; raw barriers carry no implicit drain). Both-sides XOR swizzle: physical
// byte = logical ^ (row bits 2,3 -> col byte bits 5,4); applied on gld source
// (linear LDS dest) and on ds_read address (bijective involution, G4/T2/m204).
// Race-freedom: stage targets the buffer whose readers all finished before the
// previous barrier; reads of staged data happen only after the K-tile vmcnt(0).
__global__ __launch_bounds__(512, 1) void k_proj8(const __hip_bfloat16* __restrict__ Ap,
                                                  const __hip_bfloat16* __restrict__ BTp,
                                                  const float* __restrict__ bout,
                                                  float* __restrict__ C) {
  __shared__ __align__(16) char LDS[2][2][32768];  // [dbuf][0=A,1=B][256 rows][64 cols] bf16
  int tid = threadIdx.x;
  int lane = tid & 63;
  int wave = tid >> 6;
  int wm = wave >> 2;   // 0..1 -> rows wm*128..+128
  int wn = wave & 3;    // 0..3 -> cols wn*64..+64
  int m0 = blockIdx.x * 256;
  int n0 = blockIdx.y * 256;
  const char* Ab = (const char*)Ap;
  const char* Bb = (const char*)BTp;

  f32x4 acc[8][4] = {};

  // stage one operand (32KB, 4 gld_lds16/thread) of k-tile kt into buffer d
  auto STAGE = [&](int d, int op, int kt) {
    const char* base = op ? Bb : Ab;
    int r0 = op ? n0 : m0;
#pragma unroll
    for (int j = 0; j < 4; ++j) {
      int o = j * 8192 + wave * 1024;                 // wave-uniform LDS offset
      int q = o + lane * 16;                          // lane's linear chunk
      int qp = q ^ (((q >> 9) & 1) << 5) ^ (((q >> 10) & 1) << 4);
      int row = qp >> 7;
      int scol = qp & 127;
      gld_lds16(base + ((size_t)(r0 + row) * 512 + kt * 64) * 2 + scol,
                &LDS[d][op][o]);
    }
  };

  // prologue: k-tile 0 into buffer 0
  STAGE(0, 0, 0);
  STAGE(0, 1, 0);
  asm volatile("s_waitcnt vmcnt(0)" ::: "memory");
  __builtin_amdgcn_s_barrier();

#pragma unroll 1
  for (int t = 0; t < 8; ++t) {
    int d = t & 1;
    char* Abuf = &LDS[d][0][0];
    char* Bbuf = &LDS[d][1][0];
#pragma unroll
    for (int ph = 0; ph < 4; ++ph) {
      int qr = ph >> 1, qc = ph & 1;
      int cb0 = (lane >> 4) << 4;
      bf16x8 af[4][2], bfr[2][2];
#pragma unroll
      for (int kk = 0; kk < 2; ++kk) {
#pragma unroll
        for (int mi = 0; mi < 4; ++mi) {
          int row = wm * 128 + qr * 64 + mi * 16 + (lane & 15);
          int p = row * 128 + kk * 64 + cb0;
          p = p ^ (((p >> 9) & 1) << 5) ^ (((p >> 10) & 1) << 4);
          af[mi][kk] = *(const bf16x8*)&Abuf[p];
        }
#pragma unroll
        for (int ni = 0; ni < 2; ++ni) {
          int row = wn * 64 + qc * 32 + ni * 16 + (lane & 15);
          int p = row * 128 + kk * 64 + cb0;
          p = p ^ (((p >> 9) & 1) << 5) ^ (((p >> 10) & 1) << 4);
          bfr[ni][kk] = *(const bf16x8*)&Bbuf[p];
        }
      }
      if (ph < 2 && t < 7) STAGE(d ^ 1, ph, t + 1);   // prefetch next k-tile
      __builtin_amdgcn_s_setprio(1);
#pragma unroll
      for (int kk = 0; kk < 2; ++kk)
#pragma unroll
        for (int mi = 0; mi < 4; ++mi)
#pragma unroll
          for (int ni = 0; ni < 2; ++ni)
            acc[qr * 4 + mi][qc * 2 + ni] =
                __builtin_amdgcn_mfma_f32_16x16x32_bf16(bfr[ni][kk], af[mi][kk],
                                                        acc[qr * 4 + mi][qc * 2 + ni],
                                                        0, 0, 0);
      __builtin_amdgcn_s_setprio(0);
      if (ph == 3) asm volatile("s_waitcnt vmcnt(0)" ::: "memory");
      __builtin_amdgcn_s_barrier();
    }
  }

  // epilogue (swapped-operand layout, proven): lane holds 4 consecutive C cols.
#pragma unroll
  for (int fc = 0; fc < 4; ++fc) {
    int colbase = n0 + wn * 64 + fc * 16 + ((lane >> 4) << 2);
    float4 bb = *(const float4*)&bout[colbase];
#pragma unroll
    for (int fr = 0; fr < 8; ++fr) {
      int row = m0 + wm * 128 + fr * 16 + (lane & 15);
      f32x4 v;
      v.x = acc[fr][fc][0] + bb.x;
      v.y = acc[fr][fc][1] + bb.y;
      v.z = acc[fr][fc][2] + bb.z;
      v.w = acc[fr][fc][3] + bb.w;
      __builtin_nontemporal_store(v, (f32x4*)&C[(size_t)row * V_ + colbase]);
    }
  }
}

extern "C" void kernel_launch(void* const* d_in, const int* in_sizes, int n_in,
                              void* d_out, int out_size, void* d_ws, size_t ws_size,
                              hipStream_t stream) {
  const int* widx = (const int*)d_in[0];
  const int* num_words = (const int*)d_in[1];
  const float* enc = (const float*)d_in[2];
  const float* embW = (const float*)d_in[3];
  const float* Wg = (const float*)d_in[4];
  const float* bg = (const float*)d_in[5];
  const float* Wc = (const float*)d_in[6];
  const float* bc = (const float*)d_in[7];
  const float* Wout = (const float*)d_in[8];
  const float* bout = (const float*)d_in[9];
  float* out = (float*)d_out;

  char* ws = (char*)d_ws;
  float* pre_g = (float*)(ws);                              // 8,388,608
  float* pre_c = (float*)(ws + 8388608);                    // 4,194,304
  __hip_bfloat16* A = (__hip_bfloat16*)(ws + 12582912);     // 2,097,152
  __hip_bfloat16* WoutT = (__hip_bfloat16*)(ws + 14680064); // 32,768,000
  uint4* Wg2 = (uint4*)(ws + 47448064);                     // 1,048,576
  uint4* Wc2 = (uint4*)(ws + 48496640);                     //   524,288
  u32t* RHT = (u32t*)(ws + 49020928);                       //    65,536
  u32t* HBT = (u32t*)(ws + 49086464);                       //    65,536

  hipLaunchKernelGGL(k_setup, dim3(5984), dim3(256), 0, stream,
                     Wout, WoutT, Wg, Wc, enc, Wg2, Wc2, HBT, RHT,
                     widx, embW, bg, bc, pre_g, pre_c);
  hipLaunchKernelGGL(k_gru7, dim3(32 * NSL), dim3(512), 0, stream,
                     num_words, Wg2, Wc2, pre_g, pre_c, RHT, HBT, (u32t*)A);
  hipLaunchKernelGGL(k_proj8, dim3(8, 125), dim3(512), 0, stream, A, WoutT, bout, out);
}

// Round 16
// 378.380 us; speedup vs baseline: 1.1024x; 1.1024x over previous
//
#include <hip/hip_runtime.h>
#include <hip/hip_bf16.h>

#define V_ 32000
#define D_ 256
#define H_ 512
#define B_ 32
#define T_ 64
#define NSL 8   // column slices per batch; GRU grid = 32*NSL = 256

typedef __attribute__((ext_vector_type(8))) __bf16 bf16x8;
typedef __attribute__((ext_vector_type(4))) float f32x4;
typedef _Float16 f16x2 __attribute__((ext_vector_type(2)));
typedef unsigned int u32t;
typedef unsigned short u16t;
typedef unsigned long long u64t;

__device__ __forceinline__ u32t pack_h16(float a, float b) {
  union { _Float16 h; unsigned short u; } lo, hi;
  lo.h = (_Float16)a; hi.h = (_Float16)b;
  return (u32t)lo.u | ((u32t)hi.u << 16);
}

__device__ __forceinline__ float f16u_to_f(u16t u) {
  union { _Float16 h; unsigned short u; } x;
  x.u = u;
  return (float)x.h;
}

__device__ __forceinline__ float dot2(u32t w, u32t h, float acc) {
#if __has_builtin(__builtin_amdgcn_fdot2)
  return __builtin_amdgcn_fdot2(__builtin_bit_cast(f16x2, w),
                                __builtin_bit_cast(f16x2, h), acc, false);
#else
  f16x2 a = __builtin_bit_cast(f16x2, w);
  f16x2 b = __builtin_bit_cast(f16x2, h);
  return acc + (float)a.x * (float)b.x + (float)a.y * (float)b.y;
#endif
}

__device__ __forceinline__ void gld_lds16(const void* g, void* l) {
  __builtin_amdgcn_global_load_lds((const __attribute__((address_space(1))) void*)g,
                                   (__attribute__((address_space(3))) void*)l,
                                   16, 0, 0);
}

__device__ __forceinline__ u32t ld_rlx(const u32t* p) {
  return __hip_atomic_load(p, __ATOMIC_RELAXED, __HIP_MEMORY_SCOPE_AGENT);
}
__device__ __forceinline__ void st_rlx(u32t* p, u32t v) {
  __hip_atomic_store(p, v, __ATOMIC_RELAXED, __HIP_MEMORY_SCOPE_AGENT);
}

// ---------------- merged setup: transpose + weight packs/init + x-projections -------
// blocks [0,4000):      Wout -> WoutT transpose (500 x 8 tile grid)
// blocks [4000,4448):   Wg/Wc f16 packs + tagged HBT/RHT init
// blocks [4448,5984):   pre_g / pre_c x-projections (256 x 6)
__global__ __launch_bounds__(256) void k_setup(const float* __restrict__ Wout,
                                               __hip_bfloat16* __restrict__ WoutT,
                                               const float* __restrict__ Wg,
                                               const float* __restrict__ Wc,
                                               const float* __restrict__ enc,
                                               uint4* __restrict__ Wg2,
                                               uint4* __restrict__ Wc2,
                                               u32t* __restrict__ HBT,
                                               u32t* __restrict__ RHT,
                                               const int* __restrict__ widx,
                                               const float* __restrict__ embW,
                                               const float* __restrict__ bg,
                                               const float* __restrict__ bc,
                                               float* __restrict__ pre_g,
                                               float* __restrict__ pre_c) {
  int blk = blockIdx.x;
  int tid = threadIdx.x;

  if (blk < 4000) {
    __shared__ float tile[64][65];
    int v0 = (blk % 500) * 64;
    int h0 = (blk / 500) * 64;
#pragma unroll
    for (int i = 0; i < 16; ++i) {
      int idx = i * 256 + tid;
      int r = idx >> 6;
      int c = idx & 63;
      tile[r][c] = Wout[(size_t)(h0 + r) * V_ + v0 + c];
    }
    __syncthreads();
#pragma unroll
    for (int i = 0; i < 16; ++i) {
      int idx = i * 256 + tid;
      int rv = idx >> 6;
      int ch = idx & 63;
      WoutT[(size_t)(v0 + rv) * H_ + h0 + ch] = __float2bfloat16(tile[ch][rv]);
    }
  } else if (blk < 4448) {
    int pblk = blk - 4000;
    if (pblk < 256) {
      int gid = pblk * 256 + tid;
      int ks = gid & 3;
      int cq = (gid >> 2) & 127;
      int it = (gid >> 9) & 15;
      int s = gid >> 13;
      int j = (cq < 64) ? (s * 64 + cq) : (512 + s * 64 + (cq - 64));
      int k0 = ks * 128 + it * 8;
      uint4 v;
      v.x = pack_h16(Wg[(size_t)(256 + k0 + 0) * 1024 + j], Wg[(size_t)(256 + k0 + 1) * 1024 + j]);
      v.y = pack_h16(Wg[(size_t)(256 + k0 + 2) * 1024 + j], Wg[(size_t)(256 + k0 + 3) * 1024 + j]);
      v.z = pack_h16(Wg[(size_t)(256 + k0 + 4) * 1024 + j], Wg[(size_t)(256 + k0 + 5) * 1024 + j]);
      v.w = pack_h16(Wg[(size_t)(256 + k0 + 6) * 1024 + j], Wg[(size_t)(256 + k0 + 7) * 1024 + j]);
      Wg2[gid] = v;
    } else if (pblk < 384) {
      int gid = (pblk - 256) * 256 + tid;
      int ks8 = gid & 7;
      int cq2 = (gid >> 3) & 63;
      int it = (gid >> 9) & 7;
      int s = gid >> 12;
      int jc = s * 64 + cq2;
      int k0 = ks8 * 64 + it * 8;
      uint4 v;
      v.x = pack_h16(Wc[(size_t)(256 + k0 + 0) * 512 + jc], Wc[(size_t)(256 + k0 + 1) * 512 + jc]);
      v.y = pack_h16(Wc[(size_t)(256 + k0 + 2) * 512 + jc], Wc[(size_t)(256 + k0 + 3) * 512 + jc]);
      v.z = pack_h16(Wc[(size_t)(256 + k0 + 4) * 512 + jc], Wc[(size_t)(256 + k0 + 5) * 512 + jc]);
      v.w = pack_h16(Wc[(size_t)(256 + k0 + 6) * 512 + jc], Wc[(size_t)(256 + k0 + 7) * 512 + jc]);
      Wc2[gid] = v;
    } else {
      int gid = (pblk - 384) * 256 + tid;
      int b = gid >> 9, k = gid & 511;
      u32t hv = pack_h16(enc[b * H_ + k], 0.f) & 0xffffu;
      st_rlx(&HBT[gid], hv);
      st_rlx(&RHT[gid], 0xFFFF0000u);
    }
  } else {
    __shared__ __align__(16) float x2[D_][8];
    __shared__ int wid[8];
    int idx = blk - 4448;
    int bx = idx & 255;
    int by = idx >> 8;
    int n0 = bx * 8;
    if (tid < 8) wid[tid] = widx[n0 + tid];
    __syncthreads();
#pragma unroll
    for (int i = 0; i < 8; ++i)
      x2[tid][i] = embW[(size_t)wid[i] * D_ + tid];
    __syncthreads();

    float acc[8];
    if (by < 4) {
      int J = by * 256 + tid;
      float bias = bg[J];
#pragma unroll
      for (int i = 0; i < 8; ++i) acc[i] = bias;
      for (int d = 0; d < D_; ++d) {
        float4 xa = *(const float4*)&x2[d][0];
        float4 xb = *(const float4*)&x2[d][4];
        float w = Wg[(size_t)d * 1024 + J];
        acc[0] = fmaf(xa.x, w, acc[0]); acc[1] = fmaf(xa.y, w, acc[1]);
        acc[2] = fmaf(xa.z, w, acc[2]); acc[3] = fmaf(xa.w, w, acc[3]);
        acc[4] = fmaf(xb.x, w, acc[4]); acc[5] = fmaf(xb.y, w, acc[5]);
        acc[6] = fmaf(xb.z, w, acc[6]); acc[7] = fmaf(xb.w, w, acc[7]);
      }
#pragma unroll
      for (int i = 0; i < 8; ++i)
        pre_g[(size_t)(n0 + i) * 1024 + J] = acc[i];
    } else {
      int Jc = (by - 4) * 256 + tid;
      float bias = bc[Jc];
#pragma unroll
      for (int i = 0; i < 8; ++i) acc[i] = bias;
      for (int d = 0; d < D_; ++d) {
        float4 xa = *(const float4*)&x2[d][0];
        float4 xb = *(const float4*)&x2[d][4];
        float w = Wc[(size_t)d * 512 + Jc];
        acc[0] = fmaf(xa.x, w, acc[0]); acc[1] = fmaf(xa.y, w, acc[1]);
        acc[2] = fmaf(xa.z, w, acc[2]); acc[3] = fmaf(xa.w, w, acc[3]);
        acc[4] = fmaf(xb.x, w, acc[4]); acc[5] = fmaf(xb.y, w, acc[5]);
        acc[6] = fmaf(xb.z, w, acc[6]); acc[7] = fmaf(xb.w, w, acc[7]);
      }
#pragma unroll
      for (int i = 0; i < 8; ++i)
        pre_c[(size_t)(n0 + i) * 512 + Jc] = acc[i];
    }
  }
}

// ---------------- GRU v7: tag-embedded payload exchange (proven ~196 us) ------------
__global__ __launch_bounds__(512, 2) void k_gru7(const int* __restrict__ num_words,
                                                 const uint4* __restrict__ Wg2,
                                                 const uint4* __restrict__ Wc2,
                                                 const float* __restrict__ pre_g,
                                                 const float* __restrict__ pre_c,
                                                 u32t* __restrict__ RHT,
                                                 u32t* __restrict__ HBT,
                                                 u32t* __restrict__ A32) {
  __shared__ __align__(16) u32t h2_l[256];
  __shared__ __align__(16) u32t rh2_l[256];
  __shared__ float u_l[64];
  int bid = blockIdx.x;
  int b = bid & 31;
  int s = bid >> 5;
  int tid = threadIdx.x;
  int nw = num_words[b];

  int cq = tid >> 2, ks = tid & 3;
  int j1 = (cq < 64) ? (s * 64 + cq) : (512 + s * 64 + (cq - 64));
  int cq2 = tid >> 3, ks8 = tid & 7;
  int jc = s * 64 + cq2;

  uint4 wg[16];
#pragma unroll
  for (int i = 0; i < 16; ++i) {
    int ii = (i + ks) & 15;
    wg[i] = Wg2[(((size_t)s * 16 + ii) * 128 + cq) * 4 + ks];
  }
  uint4 wc[8];
#pragma unroll
  for (int i = 0; i < 8; ++i) {
    int ii = (i + ks8) & 7;
    wc[i] = Wc2[(((size_t)s * 8 + ii) * 64 + cq2) * 8 + ks8];
  }

  u32t* HBp = HBT + (size_t)b * 512;
  u32t* RHp = RHT + (size_t)b * 512;
  bool pub1 = (ks == 0) && (cq < 64);
  bool ulane = (ks == 0) && (cq >= 64);
  bool pub2 = (ks8 == 0);
  bool writer2 = pub2 && ((cq2 & 1) == 0);

  for (int t = 0; t < T_; ++t) {
    float pg = pre_g[((size_t)b * T_ + t) * 1024 + j1];
    float pc = pre_c[((size_t)b * T_ + t) * 512 + jc];

    __syncthreads();
    {
      u32t want = (u32t)t << 16;
      u32t v;
      do { v = ld_rlx(&HBp[tid]); } while ((v & 0xffff0000u) != want);
      ((volatile u16t*)h2_l)[tid] = (u16t)v;
    }
    __syncthreads();

    float a0 = 0.f, a1 = 0.f, a2s = 0.f, a3 = 0.f;
    const uint4* h4 = (const uint4*)h2_l;
#pragma unroll
    for (int i = 0; i < 16; ++i) {
      int ii = (i + ks) & 15;
      uint4 hv = h4[ks * 16 + ii];
      a0 = dot2(wg[i].x, hv.x, a0);
      a1 = dot2(wg[i].y, hv.y, a1);
      a2s = dot2(wg[i].z, hv.z, a2s);
      a3 = dot2(wg[i].w, hv.w, a3);
    }
    float a = (a0 + a1) + (a2s + a3);
    a += __shfl_xor(a, 1);
    a += __shfl_xor(a, 2);
    float gate = 1.f / (1.f + __expf(-(a + pg)));
    if (cq < 64) {
      float hh = f16u_to_f(((const u16t*)h2_l)[s * 64 + cq]);
      if (pub1)
        st_rlx(&RHp[s * 64 + cq],
               (pack_h16(gate * hh, 0.f) & 0xffffu) | ((u32t)(t + 1) << 16));
    } else if (ulane) {
      u_l[cq - 64] = gate;
    }

    {
      u32t want = (u32t)(t + 1) << 16;
      u32t v;
      do { v = ld_rlx(&RHp[tid]); } while ((v & 0xffff0000u) != want);
      ((volatile u16t*)rh2_l)[tid] = (u16t)v;
    }
    __syncthreads();

    float c0 = 0.f, c1 = 0.f, c2 = 0.f, c3 = 0.f;
    const uint4* r4 = (const uint4*)rh2_l;
#pragma unroll
    for (int i = 0; i < 8; ++i) {
      int ii = (i + ks8) & 7;
      uint4 rv = r4[ks8 * 8 + ii];
      c0 = dot2(wc[i].x, rv.x, c0);
      c1 = dot2(wc[i].y, rv.y, c1);
      c2 = dot2(wc[i].z, rv.z, c2);
      c3 = dot2(wc[i].w, rv.w, c3);
    }
    float a2 = (c0 + c1) + (c2 + c3);
    a2 += __shfl_xor(a2, 1);
    a2 += __shfl_xor(a2, 2);
    a2 += __shfl_xor(a2, 4);
    float cv = tanhf(a2 + pc);
    float uu = u_l[cq2];
    float hold = f16u_to_f(((const u16t*)h2_l)[jc]);
    float hn = uu * hold + (1.f - uu) * cv;
    bool live = t < nw;
    float hnext = live ? hn : hold;
    if (pub2)
      st_rlx(&HBp[s * 64 + cq2],
             (pack_h16(hnext, 0.f) & 0xffffu) | ((u32t)(t + 1) << 16));
    u32t ma = (u32t)__hip_bfloat16_raw(__float2bfloat16(live ? hn : 0.f)).x;
    u32t oa = (u32t)__shfl_xor((int)ma, 8);
    if (writer2)
      A32[(((size_t)b * T_ + t) * 512 + jc) >> 1] = ma | (oa << 16);
  }
}

// ---------------- projection (round-13 proven structure + XCD-chunked swizzle) ------
// 1D grid 4000; tau = (bid%8)*500 + bid/8 (bijective, 4000%8==0), n-major tau = n*16+m:
// each XCD gets ~31 consecutive n-tiles (~4MB of B = one L2) -> B L2-resident per XCD.
// Swapped MFMA operands: lane holds 4 consecutive C columns -> one dwordx4 NT store.
__global__ __launch_bounds__(256) void k_proj(const __hip_bfloat16* __restrict__ Ap,
                                              const __hip_bfloat16* __restrict__ BTp,
                                              const float* __restrict__ bout,
                                              float* __restrict__ C) {
  __shared__ char As[128 * 64 * 2];
  __shared__ char Bs[128 * 64 * 2];
  int tid = threadIdx.x;
  int lane = tid & 63;
  int wave = tid >> 6;
  int bid = blockIdx.x;
  int tau = (bid & 7) * 500 + (bid >> 3);  // XCD-chunked (nwg=4000, 8 XCDs)
  int m = tau & 15;
  int n = tau >> 4;
  int m0 = m * 128;
  int n0 = n * 128;
  int wm = wave >> 1, wn = wave & 1;
  f32x4 acc[4][4] = {};

  const char* Ab = (const char*)Ap;
  const char* Bb = (const char*)BTp;

  for (int ks = 0; ks < 8; ++ks) {
    int k0 = ks * 64;
    __syncthreads();
#pragma unroll
    for (int inst = 0; inst < 4; ++inst) {
      int o = inst * 4096 + wave * 1024;
      int ol = o + lane * 16;
      int r = ol >> 7;
      int cb = ol & 127;
      gld_lds16(Ab + ((size_t)(m0 + r) * 512 + k0) * 2 + cb, As + o);
      gld_lds16(Bb + ((size_t)(n0 + r) * 512 + k0) * 2 + cb, Bs + o);
    }
    __syncthreads();
#pragma unroll
    for (int kk = 0; kk < 64; kk += 32) {
      bf16x8 af[4], bfr[4];
      int cbyte = kk * 2 + ((lane >> 4) << 4);
#pragma unroll
      for (int mi = 0; mi < 4; ++mi) {
        int row = wm * 64 + mi * 16 + (lane & 15);
        af[mi] = *(const bf16x8*)(As + row * 128 + cbyte);
      }
#pragma unroll
      for (int ni = 0; ni < 4; ++ni) {
        int row = wn * 64 + ni * 16 + (lane & 15);
        bfr[ni] = *(const bf16x8*)(Bs + row * 128 + cbyte);
      }
#pragma unroll
      for (int mi = 0; mi < 4; ++mi)
#pragma unroll
        for (int ni = 0; ni < 4; ++ni)
          acc[mi][ni] = __builtin_amdgcn_mfma_f32_16x16x32_bf16(bfr[ni], af[mi], acc[mi][ni], 0, 0, 0);
    }
  }
#pragma unroll
  for (int ni = 0; ni < 4; ++ni) {
    int colbase = n0 + wn * 64 + ni * 16 + ((lane >> 4) << 2);
    float4 bb = *(const float4*)&bout[colbase];
#pragma unroll
    for (int mi = 0; mi < 4; ++mi) {
      int row = m0 + wm * 64 + mi * 16 + (lane & 15);
      f32x4 v;
      v.x = acc[mi][ni][0] + bb.x;
      v.y = acc[mi][ni][1] + bb.y;
      v.z = acc[mi][ni][2] + bb.z;
      v.w = acc[mi][ni][3] + bb.w;
      __builtin_nontemporal_store(v, (f32x4*)&C[(size_t)row * V_ + colbase]);
    }
  }
}

extern "C" void kernel_launch(void* const* d_in, const int* in_sizes, int n_in,
                              void* d_out, int out_size, void* d_ws, size_t ws_size,
                              hipStream_t stream) {
  const int* widx = (const int*)d_in[0];
  const int* num_words = (const int*)d_in[1];
  const float* enc = (const float*)d_in[2];
  const float* embW = (const float*)d_in[3];
  const float* Wg = (const float*)d_in[4];
  const float* bg = (const float*)d_in[5];
  const float* Wc = (const float*)d_in[6];
  const float* bc = (const float*)d_in[7];
  const float* Wout = (const float*)d_in[8];
  const float* bout = (const float*)d_in[9];
  float* out = (float*)d_out;

  char* ws = (char*)d_ws;
  float* pre_g = (float*)(ws);                              // 8,388,608
  float* pre_c = (float*)(ws + 8388608);                    // 4,194,304
  __hip_bfloat16* A = (__hip_bfloat16*)(ws + 12582912);     // 2,097,152
  __hip_bfloat16* WoutT = (__hip_bfloat16*)(ws + 14680064); // 32,768,000
  uint4* Wg2 = (uint4*)(ws + 47448064);                     // 1,048,576
  uint4* Wc2 = (uint4*)(ws + 48496640);                     //   524,288
  u32t* RHT = (u32t*)(ws + 49020928);                       //    65,536
  u32t* HBT = (u32t*)(ws + 49086464);                       //    65,536

  hipLaunchKernelGGL(k_setup, dim3(5984), dim3(256), 0, stream,
                     Wout, WoutT, Wg, Wc, enc, Wg2, Wc2, HBT, RHT,
                     widx, embW, bg, bc, pre_g, pre_c);
  hipLaunchKernelGGL(k_gru7, dim3(32 * NSL), dim3(512), 0, stream,
                     num_words, Wg2, Wc2, pre_g, pre_c, RHT, HBT, (u32t*)A);
  hipLaunchKernelGGL(k_proj, dim3(4000), dim3(256), 0, stream, A, WoutT, bout, out);
}